// Round 12
// baseline (69.162 us; speedup 1.0000x reference)
//
#include <hip/hip_runtime.h>
#include <hip/hip_bf16.h>

#define B_ 8
#define W_ 128
#define K_ 2048
#define D_ 256
#define WX 144            // padded w-dim: 128 x-cols + E1-col(128) + 15 zero cols
#define NC 256            // K/8 j-chunks
#define RP 24             // epilogue LDS row-pitch (floats); 16B-aligned f32x4 slots

typedef __attribute__((ext_vector_type(8))) short bf16x8;
typedef __attribute__((ext_vector_type(4))) float f32x4;

static __device__ __forceinline__ short f2bf(float f) {
    unsigned int u = __float_as_uint(f);
    unsigned int r = (u + 0x7FFFu + ((u >> 16) & 1u)) >> 16;
    return (short)r;
}

// ---------- k_w2v: w2v[w] = sum_d W_lin[W+w][d] * a[d]  (128 blocks x 1 wave)
__global__ void k_w2v(const float* __restrict__ W_lin, const float* __restrict__ a,
                      float* __restrict__ w2v) {
    int w = blockIdx.x, l = threadIdx.x;
    float4 rv = ((const float4*)(W_lin + (size_t)(W_ + w) * D_))[l];
    float4 av = ((const float4*)a)[l];
    float acc = rv.x * av.x + rv.y * av.y + rv.z * av.z + rv.w * av.w;
    for (int m = 1; m < 64; m <<= 1) acc += __shfl_xor(acc, m);
    if (l == 0) w2v[w] = acc;
}

// ---------- k_pe: heterogeneous grid (768 blocks x 512 thr)  [unchanged from r11]
__global__ __launch_bounds__(512) void k_pe(const float* __restrict__ x,
        const float* __restrict__ w2v, const float* __restrict__ bias,
        short* __restrict__ xbt, short* __restrict__ e2t) {
    __shared__ float sc[696];
    int tid = threadIdx.x;
    int wid = tid >> 6;
    int lane = tid & 63;

    if (blockIdx.x < 512) {
        // ---- prep: this block owns 32 k-cols ----
        if (tid < W_) sc[tid] = w2v[tid];          // ws
        __syncthreads();
        int q = tid & 31, cw = tid >> 5;           // cw 0..15, 8 w each
        int bk0 = blockIdx.x * 32;
        int b = bk0 >> 11;
        int k = (bk0 & (K_ - 1)) + q;
        const float* xp = x + ((size_t)b * W_ + cw * 8) * K_ + k;
        float xv[8];
        float acc = 0.f;
#pragma unroll
        for (int w = 0; w < 8; ++w) {
            xv[w] = xp[(size_t)w * K_];
            acc += xv[w] * sc[cw * 8 + w];
        }
        sc[128 + cw * 33 + q] = acc;               // red[16][33]
        __syncthreads();
        if (tid < 32) {
            float s = 0.f;
#pragma unroll
            for (int cc = 0; cc < 16; ++cc) s += sc[128 + cc * 33 + tid];
            sc[656 + tid] = __expf(s);             // e1s; |u2| small, shift-invariant
        }
        __syncthreads();
        float e1q = sc[656 + q];
        short* xo = xbt + (((size_t)b * NC + (k >> 3)) * WX + cw * 8) * 8 + (k & 7);
#pragma unroll
        for (int w = 0; w < 8; ++w) xo[w * 8] = f2bf(xv[w] * e1q);
        if (tid < 32) {   // E1 column (w=128)
            int kk = (bk0 & (K_ - 1)) + tid;
            xbt[(((size_t)b * NC + (kk >> 3)) * WX + 128) * 8 + (kk & 7)] = f2bf(sc[656 + tid]);
        }
        if (tid >= 64 && tid < 124) {   // zero cols 129..143, this block's 4 c-chunks
            int id = tid - 64;
            int cl = id / 15, wz = 129 + id % 15;
            int c = ((bk0 & (K_ - 1)) >> 3) + cl;
            bf16x8 z = {0, 0, 0, 0, 0, 0, 0, 0};
            *(bf16x8*)(xbt + (((size_t)b * NC + c) * WX + wz) * 8) = z;
        }
    } else {
        // ---- e2: 8 rows per block (256 blocks), 64-B write runs ----
        int i0e = (blockIdx.x - 512) * 8;
        {
            const float4* bp = (const float4*)(bias + (size_t)(i0e + wid) * K_);
            float m = -1e30f;
#pragma unroll
            for (int s = 0; s < 8; ++s) {
                float4 v = bp[lane + s * 64];
                m = fmaxf(m, fmaxf(fmaxf(v.x, v.y), fmaxf(v.z, v.w)));
            }
#pragma unroll
            for (int mm = 1; mm < 64; mm <<= 1) m = fmaxf(m, __shfl_xor(m, mm));
            if (lane == 0) sc[wid] = m;
        }
        __syncthreads();
        {
            int ilr = tid & 7, cg = tid >> 3;      // cg 0..63, 4 c-chunks each
            float mb = sc[ilr];
            int i = i0e + ilr;
            const float4* brow = (const float4*)(bias + (size_t)i * K_);
#pragma unroll
            for (int it = 0; it < 4; ++it) {
                int c = cg * 4 + it;
                float4 v0 = brow[c * 2];
                float4 v1 = brow[c * 2 + 1];
                bf16x8 o;
                o[0] = f2bf(__expf(v0.x - mb)); o[1] = f2bf(__expf(v0.y - mb));
                o[2] = f2bf(__expf(v0.z - mb)); o[3] = f2bf(__expf(v0.w - mb));
                o[4] = f2bf(__expf(v1.x - mb)); o[5] = f2bf(__expf(v1.y - mb));
                o[6] = f2bf(__expf(v1.z - mb)); o[7] = f2bf(__expf(v1.w - mb));
                *(bf16x8*)(e2t + ((size_t)c * K_ + i) * 8) = o;
            }
        }
    }
}

// ---------- k_gemm: D[b,i,wcol] = sum_j E2[i,j]*X'[b,wcol,j]; col 128 = l.
// grid 512 = 128 i-tiles (16 rows) x 4 b-pairs. blk: bh = blk&3 (XCD p -> bh=p&3,
// xbt working set 2 slices = 1.15MB L2-resident), it = blk>>2, i0 = it*16.
// 8 waves = 2 b (wb) x 4 j-slices (js, 512 j). Wave: full 9 n-tiles, acc 36 VGPR.
// A (e2t) addresses identical for the two b-waves -> L1 dedup -> A-traffic halved.
struct SetF { bf16x8 A; bf16x8 B0, B1, B2, B3, B4, B5, B6, B7, B8; };

#define MF(a_, b_, c_) __builtin_amdgcn_mfma_f32_16x16x32_bf16(a_, b_, c_, 0, 0, 0)

#define FETCHF(S, c_) do {                                         \
    const short* _e = eA + (size_t)(c_) * (K_ * 8);                \
    const short* _x = xB + (size_t)(c_) * (WX * 8);                \
    S.A  = *(const bf16x8*)(_e);                                   \
    S.B0 = *(const bf16x8*)(_x);                                   \
    S.B1 = *(const bf16x8*)(_x + 128);                             \
    S.B2 = *(const bf16x8*)(_x + 256);                             \
    S.B3 = *(const bf16x8*)(_x + 384);                             \
    S.B4 = *(const bf16x8*)(_x + 512);                             \
    S.B5 = *(const bf16x8*)(_x + 640);                             \
    S.B6 = *(const bf16x8*)(_x + 768);                             \
    S.B7 = *(const bf16x8*)(_x + 896);                             \
    S.B8 = *(const bf16x8*)(_x + 1024);                            \
} while (0)

#define CONSUMEF(S) do {                                           \
    q0 = MF(S.A, S.B0, q0); q1 = MF(S.A, S.B1, q1);                \
    q2 = MF(S.A, S.B2, q2); q3 = MF(S.A, S.B3, q3);                \
    q4 = MF(S.A, S.B4, q4); q5 = MF(S.A, S.B5, q5);                \
    q6 = MF(S.A, S.B6, q6); q7 = MF(S.A, S.B7, q7);                \
    q8 = MF(S.A, S.B8, q8);                                        \
} while (0)

__global__ __launch_bounds__(512, 4) void k_gemm(const short* __restrict__ e2t,
        const short* __restrict__ xbt, float* __restrict__ out) {
    __shared__ __align__(16) char lds[36864];  // slots[4][9][64] f32x4 = 36KB; epi [2][144][RP] f32 = 27.6KB alias
    f32x4 (*slots)[9][64] = (f32x4 (*)[9][64])lds;
    int blk  = blockIdx.x;
    int bh   = blk & 3;                  // b-pair; XCD-local via round-robin dispatch
    int i0   = (blk >> 2) * 16;
    int tid  = threadIdx.x;
    int wid  = tid >> 6;
    int lane = tid & 63;
    int il   = lane & 15;
    int kg   = lane >> 4;
    int wb   = wid & 1;                  // b within pair
    int js   = wid >> 1;                 // j-slice (512 j)
    int b    = bh * 2 + wb;

    const short* eA = e2t + (((size_t)(js * 64 + kg)) * K_ + i0 + il) * 8;
    const short* xB = xbt + (((size_t)b * NC + js * 64 + kg) * WX + il) * 8;

    f32x4 q0{0,0,0,0}, q1{0,0,0,0}, q2{0,0,0,0}, q3{0,0,0,0}, q4{0,0,0,0},
          q5{0,0,0,0}, q6{0,0,0,0}, q7{0,0,0,0}, q8{0,0,0,0};

    SetF X;
#pragma unroll 2
    for (int s = 0; s < 16; ++s) {       // 16 k-steps x 32 j = 512 j
        FETCHF(X, s * 4);
        CONSUMEF(X);
    }

#define DUMPF(slot) do {                                            \
    slots[slot][0][lane] = q0; slots[slot][1][lane] = q1;           \
    slots[slot][2][lane] = q2; slots[slot][3][lane] = q3;           \
    slots[slot][4][lane] = q4; slots[slot][5][lane] = q5;           \
    slots[slot][6][lane] = q6; slots[slot][7][lane] = q7;           \
    slots[slot][8][lane] = q8; } while (0)
#define GATHF(slot) do {                                            \
    q0 += slots[slot][0][lane]; q1 += slots[slot][1][lane];         \
    q2 += slots[slot][2][lane]; q3 += slots[slot][3][lane];         \
    q4 += slots[slot][4][lane]; q5 += slots[slot][5][lane];         \
    q6 += slots[slot][6][lane]; q7 += slots[slot][7][lane];         \
    q8 += slots[slot][8][lane]; } while (0)

    // two parallel trees (one per b): 4 -> 2 -> 1
    if (js >= 2) DUMPF(wb * 2 + (js - 2));
    __syncthreads();
    if (js < 2) GATHF(wb * 2 + js);
    __syncthreads();
    if (js == 1) DUMPF(wb * 2);
    __syncthreads();
    if (js == 0) GATHF(wb * 2);
    __syncthreads();                     // all slot reads retired before epi overwrite

    float* epi = (float*)lds;            // [wb][col 144][RP]
    if (js == 0) {
#define WRF(n_, q_) *(f32x4*)(epi + ((size_t)(wb * 144 + (n_) * 16 + il)) * RP + kg * 4) = q_
        WRF(0, q0); WRF(1, q1); WRF(2, q2); WRF(3, q3); WRF(4, q4);
        WRF(5, q5); WRF(6, q6); WRF(7, q7); WRF(8, q8);
    }
    __syncthreads();

    // epilogue: 512 thr x 2 b: col = tid>>2 (0..127), rows rs..rs+3; l in col 128
    {
        int col = tid >> 2;
        int rs  = (tid & 3) * 4;
#pragma unroll
        for (int wbb = 0; wbb < 2; ++wbb) {
            f32x4 nv = *(const f32x4*)(epi + ((size_t)(wbb * 144 + col)) * RP + rs);
            f32x4 lv = *(const f32x4*)(epi + ((size_t)(wbb * 144 + 128)) * RP + rs);
            float4 o;
            o.x = 1.f / (1.f + __expf(-nv[0] / lv[0]));
            o.y = 1.f / (1.f + __expf(-nv[1] / lv[1]));
            o.z = 1.f / (1.f + __expf(-nv[2] / lv[2]));
            o.w = 1.f / (1.f + __expf(-nv[3] / lv[3]));
            float* op = out + ((size_t)(bh * 2 + wbb) * W_ + col) * K_ + i0 + rs;
            *(float4*)op = o;
        }
    }
}

extern "C" void kernel_launch(void* const* d_in, const int* in_sizes, int n_in,
                              void* d_out, int out_size, void* d_ws, size_t ws_size,
                              hipStream_t stream) {
    const float* x     = (const float*)d_in[0];
    const float* W_lin = (const float*)d_in[1];
    // d_in[2] = b_lin: constant along softmax axis -> cancels, unused
    const float* a     = (const float*)d_in[3];
    const float* bias  = (const float*)d_in[4];
    float* out = (float*)d_out;

    float* w2v = (float*)d_ws;                    // 128 f32
    short* xbt = (short*)(w2v + 128);             // 8*256*144*8 bf16 = 4.72 MB
    short* e2t = xbt + (size_t)B_ * NC * WX * 8;  // 256*2048*8 bf16 = 8 MB

    k_w2v <<<128, 64, 0, stream>>>(W_lin, a, w2v);
    k_pe  <<<768, 512, 0, stream>>>(x, w2v, bias, xbt, e2t);
    k_gemm<<<512, 512, 0, stream>>>(e2t, xbt, out);
}